// Round 6
// baseline (2412.994 us; speedup 1.0000x reference)
//
#include <hip/hip_runtime.h>

typedef unsigned short u16;
typedef __attribute__((ext_vector_type(8))) short short8;
typedef __attribute__((ext_vector_type(4))) float floatx4;

#define CDIM 1024
#define NB 4

__device__ __forceinline__ float bf2f(u16 u) {
  union { unsigned int i; float f; } v; v.i = ((unsigned int)u) << 16; return v.f;
}
__device__ __forceinline__ u16 f2bf(float f) {
  union { float f; unsigned int i; } v; v.f = f;
  unsigned int r = v.i + 0x7fffu + ((v.i >> 16) & 1u);
  return (u16)(r >> 16);
}
__device__ __forceinline__ float san(float f) {
  return (fabsf(f) <= 3.0e38f) ? f : 0.f;
}
// dtype-flagged input load: flag 1 = fp32, 0 = bf16
__device__ __forceinline__ float ldin(const void* p, size_t i, int f) {
  return f ? san(((const float*)p)[i]) : bf2f(((const u16*)p)[i]);
}

// ---------------- per-tensor dtype sniffer ----------------
struct PtrArgs { const void* p[22]; int n[22]; };

__global__ void detect_dtypes(PtrArgs a, int* __restrict__ flags) {
  __shared__ int cnt;
  int ti = blockIdx.x;
  if (threadIdx.x == 0) cnt = 0;
  __syncthreads();
  if (ti >= 22) {
    if (threadIdx.x == 0) flags[ti] = 0;
    return;
  }
  const u16* u = (const u16*)a.p[ti];
  int m = a.n[ti]; if (m > 4096) m = 4096;
  int local = 0;
  for (int i = threadIdx.x; i < m; i += blockDim.x) {
    int e = (u[i] >> 7) & 0xFF;
    if (e != 0 && (e < 97 || e > 158)) local++;
  }
  atomicAdd(&cnt, local);
  __syncthreads();
  if (threadIdx.x == 0) flags[ti] = (cnt >= (m >> 6) + 2) ? 1 : 0;
}

// ---------------- transpose + zero-pad (dtype-flagged input -> bf16) ----
// in: (NB, C, Lin) ; out: (NB, Lout, C) bf16, rows >= Lin zeroed.
__global__ void transpose_pad(const void* __restrict__ inv, u16* __restrict__ out,
                              int Lin, int Lout, const int* __restrict__ flags, int fidx) {
  __shared__ u16 t[32][33];
  int f = flags[fidx];
  int b = blockIdx.z;
  int l0 = blockIdx.x * 32, c0 = blockIdx.y * 32;
  int x = threadIdx.x, y = threadIdx.y;
  bool valid = (l0 < Lin);   // Lin % 32 == 0: whole tile valid or whole tile pad
  if (valid) {
    for (int r = 0; r < 4; r++) {
      size_t idx = ((size_t)b * CDIM + c0 + y * 4 + r) * Lin + l0 + x;
      t[y * 4 + r][x] = f2bf(ldin(inv, idx, f));
    }
  }
  __syncthreads();
  for (int r = 0; r < 4; r++) {
    int lr = l0 + y * 4 + r;
    out[((size_t)b * Lout + lr) * CDIM + c0 + x] = valid ? t[x][y * 4 + r] : (u16)0;
  }
}

// ---------------- bf16 MFMA GEMM with BN epilogue ----------------
// Out[b, o, l] = (sum_c Wm[o,c] * X[b,c,l]) * sc[o] + sh[o]
// Wm: (1024,1024) row-major, dtype per flag. XT: (NB*Lpad,1024) bf16.
// Out: (NB, 1024, Lpad), bf16 (f32out=0) or fp32 (f32out=1). Lpad % 128 == 0.
#define GBK 32
#define LDKP 40   // padded LDS row stride (shorts)

__global__ __launch_bounds__(256) void gemm_bn(
    const void* __restrict__ Wm, const u16* __restrict__ XT, void* __restrict__ Out,
    const void* __restrict__ sc, const void* __restrict__ sh, int Lpad,
    const int* __restrict__ flags, int wfi, int sci, int shi, int f32out) {
  __shared__ __align__(16) u16 As[128 * LDKP];
  __shared__ __align__(16) u16 Bs[128 * LDKP];
  const int K = 1024;
  int wf = flags[wfi];
  int tid = threadIdx.x;
  int lane = tid & 63, wave = tid >> 6;
  int m0 = blockIdx.y * 128, n0 = blockIdx.x * 128;
  int wm = (wave >> 1) * 64, wn = (wave & 1) * 64;
  int srow = tid >> 2, scol = (tid & 3) * 8;
  floatx4 acc[4][4] = {};
  for (int k0 = 0; k0 < K; k0 += GBK) {
    __syncthreads();
#pragma unroll
    for (int half = 0; half < 2; half++) {
      int row = srow + half * 64;
      if (wf) {
        const float* W = (const float*)Wm;
        float4 a0 = *(const float4*)&W[(size_t)(m0 + row) * K + k0 + scol];
        float4 a1 = *(const float4*)&W[(size_t)(m0 + row) * K + k0 + scol + 4];
        __align__(16) u16 tmp[8];
        tmp[0] = f2bf(san(a0.x)); tmp[1] = f2bf(san(a0.y));
        tmp[2] = f2bf(san(a0.z)); tmp[3] = f2bf(san(a0.w));
        tmp[4] = f2bf(san(a1.x)); tmp[5] = f2bf(san(a1.y));
        tmp[6] = f2bf(san(a1.z)); tmp[7] = f2bf(san(a1.w));
        *(uint4*)&As[row * LDKP + scol] = *(uint4*)tmp;
      } else {
        const u16* W = (const u16*)Wm;
        *(uint4*)&As[row * LDKP + scol] =
            *(const uint4*)&W[(size_t)(m0 + row) * K + k0 + scol];
      }
    }
    *(uint4*)&Bs[srow * LDKP + scol] =
        *(const uint4*)&XT[(size_t)(n0 + srow) * K + k0 + scol];
    *(uint4*)&Bs[(srow + 64) * LDKP + scol] =
        *(const uint4*)&XT[(size_t)(n0 + srow + 64) * K + k0 + scol];
    __syncthreads();
    int lr = lane & 15, q8 = (lane >> 4) * 8;
    short8 af[4], bfr[4];
#pragma unroll
    for (int f = 0; f < 4; f++) {
      af[f]  = *(const short8*)&As[(wm + f * 16 + lr) * LDKP + q8];
      bfr[f] = *(const short8*)&Bs[(wn + f * 16 + lr) * LDKP + q8];
    }
#pragma unroll
    for (int i = 0; i < 4; i++)
#pragma unroll
      for (int j = 0; j < 4; j++)
        acc[i][j] = __builtin_amdgcn_mfma_f32_16x16x32_bf16(af[i], bfr[j], acc[i][j], 0, 0, 0);
  }
  // epilogue: C/D layout col = lane&15, row = (lane>>4)*4 + reg  [m89-verified]
  int sf = flags[sci], hf = flags[shi];
  int colL = lane & 15, rq = (lane >> 4) * 4;
  int b = n0 / Lpad;
  int lb = n0 - b * Lpad;
#pragma unroll
  for (int i = 0; i < 4; i++) {
    int gr0 = m0 + wm + i * 16 + rq;
    float s0 = ldin(sc, gr0, sf),     h0 = ldin(sh, gr0, hf);
    float s1 = ldin(sc, gr0 + 1, sf), h1 = ldin(sh, gr0 + 1, hf);
    float s2 = ldin(sc, gr0 + 2, sf), h2 = ldin(sh, gr0 + 2, hf);
    float s3 = ldin(sc, gr0 + 3, sf), h3 = ldin(sh, gr0 + 3, hf);
#pragma unroll
    for (int j = 0; j < 4; j++) {
      int gc = lb + wn + j * 16 + colL;
      size_t base = ((size_t)b * CDIM + gr0) * Lpad + gc;
      float r0 = acc[i][j][0] * s0 + h0;
      float r1 = acc[i][j][1] * s1 + h1;
      float r2 = acc[i][j][2] * s2 + h2;
      float r3 = acc[i][j][3] * s3 + h3;
      if (f32out) {
        float* O = (float*)Out;
        O[base]                    = r0;
        O[base + (size_t)Lpad]     = r1;
        O[base + 2 * (size_t)Lpad] = r2;
        O[base + 3 * (size_t)Lpad] = r3;
      } else {
        u16* O = (u16*)Out;
        O[base]                    = f2bf(r0);
        O[base + (size_t)Lpad]     = f2bf(r1);
        O[base + 2 * (size_t)Lpad] = f2bf(r2);
        O[base + 3 * (size_t)Lpad] = f2bf(r3);
      }
    }
  }
}

// ---------------- attention P precompute ----------------
// qk: (NB,8,2,64,Lstride) bf16 ws (channel = H*128 + s*64 + d).
// P layout: [lev][bh][g][J][j] fp32, bh = b*8+H, g in [0,G).
template<int BASE>
__global__ void p_compute(const u16* __restrict__ qk, float* __restrict__ P,
                          int Lstride, int n, int G) {
  int lev = blockIdx.y;
  int t = blockIdx.x * blockDim.x + threadIdx.x;
  if (t >= 32 * G) return;
  int g = t % G, bh = t / G;
  int inner = 1;
  for (int i = 0; i < n - 1 - lev; i++) inner *= BASE;
  int ii = g / inner, kk = g - ii * inner;
  const u16* qp = qk + ((size_t)bh * 128) * Lstride;
  const u16* kp = qk + ((size_t)bh * 128 + 64) * Lstride;
  int lpos[BASE];
#pragma unroll
  for (int j = 0; j < BASE; j++) lpos[j] = (ii * BASE + j) * inner + kk;
  float S[BASE][BASE];
#pragma unroll
  for (int J = 0; J < BASE; J++)
#pragma unroll
    for (int j = 0; j < BASE; j++) S[J][j] = 0.f;
  for (int d = 0; d < 64; d++) {
    float qv[BASE], kv[BASE];
#pragma unroll
    for (int j = 0; j < BASE; j++) {
      qv[j] = bf2f(qp[(size_t)d * Lstride + lpos[j]]);
      kv[j] = bf2f(kp[(size_t)d * Lstride + lpos[j]]);
    }
#pragma unroll
    for (int J = 0; J < BASE; J++)
#pragma unroll
      for (int j = 0; j < BASE; j++) S[J][j] += kv[J] * qv[j];
  }
  float* Pg = P + ((size_t)lev * 32 * G + t) * (BASE * BASE);
#pragma unroll
  for (int J = 0; J < BASE; J++) {
    float mx = -1e30f;
#pragma unroll
    for (int j = 0; j < BASE; j++) { S[J][j] *= 0.125f; mx = fmaxf(mx, S[J][j]); }
    float e[BASE]; float sum = 0.f;
#pragma unroll
    for (int j = 0; j < BASE; j++) { e[j] = __expf(S[J][j] - mx); sum += e[j]; }
    float inv = 1.f / sum;
#pragma unroll
    for (int j = 0; j < BASE; j++) Pg[J * BASE + j] = e[j] * inv;
  }
}

// ---------------- apply one attention level to v (may be in-place) -------
template<int BASE>
__global__ void apply_level(const u16* vin, u16* vout,
                            const float* __restrict__ Plev, int inner, int G, int Lstride) {
  size_t t = (size_t)blockIdx.x * blockDim.x + threadIdx.x;
  int g = (int)(t % G);
  size_t rest = t / G;
  int d = (int)(rest & 127);
  int bh = (int)(rest >> 7);
  int ii = g / inner, kk = g - ii * inner;
  size_t rowb = ((size_t)bh * 128 + d) * Lstride;
  const float* Pg = Plev + ((size_t)bh * G + g) * (BASE * BASE);
  float vv[BASE]; int lp[BASE];
#pragma unroll
  for (int j = 0; j < BASE; j++) {
    lp[j] = (ii * BASE + j) * inner + kk;
    vv[j] = bf2f(vin[rowb + lp[j]]);
  }
#pragma unroll
  for (int J = 0; J < BASE; J++) {
    float o = 0.f;
#pragma unroll
    for (int j = 0; j < BASE; j++) o += Pg[J * BASE + j] * vv[j];
    vout[rowb + lp[J]] = f2bf(o);
  }
}

// ---------------- combine: residual + v1 + v2 + BN(dwconv3(v0)) ----------
// y[b,c,l] (stride 4096, bf16) = xres + v1 + v2 + dwconv-BN(v0)
// xres may alias y (stage 3): same-index read-then-write per thread -> safe.
__global__ void combine_pe(const void* xres, const u16* __restrict__ v1,
                           const u16* __restrict__ v2, const u16* __restrict__ v0,
                           const void* __restrict__ wpe, const void* __restrict__ spe,
                           const void* __restrict__ bpe, u16* y,
                           int Lstride, int Lv, const int* __restrict__ flags,
                           int xfi, int wpi, int spi, int bpi) {
  size_t t = (size_t)blockIdx.x * blockDim.x + threadIdx.x;
  int xf = flags[xfi], wf = flags[wpi], sf = flags[spi], bf = flags[bpi];
  int l = (int)(t & 4095);
  size_t ch = t >> 12;            // b*1024 + c
  int c = (int)(ch & 1023);
  size_t rb = ch * Lstride;
  float vm = (l > 0) ? bf2f(v0[rb + l - 1]) : 0.f;
  float vc = bf2f(v0[rb + l]);
  float vp = (l + 1 < Lv) ? bf2f(v0[rb + l + 1]) : 0.f;
  float pe = ldin(wpe, c * 3, wf) * vm + ldin(wpe, c * 3 + 1, wf) * vc +
             ldin(wpe, c * 3 + 2, wf) * vp;
  pe = pe * ldin(spe, c, sf) + ldin(bpe, c, bf);
  float xr = ldin(xres, ch * 4096 + l, xf);
  float r = xr + bf2f(v1[rb + l]) + bf2f(v2[rb + l]) + pe;
  y[ch * 4096 + l] = f2bf(r);
}

static inline int ipow(int b, int e) { int r = 1; for (int i = 0; i < e; i++) r *= b; return r; }

extern "C" void kernel_launch(void* const* d_in, const int* in_sizes, int n_in,
                              void* d_out, int out_size, void* d_ws, size_t ws_size,
                              hipStream_t stream) {
  const int W = 4096;
  const int Ls2 = 4096;                 // stage2 stride == L2
  const int L3 = 6561, Ls3 = 6656;      // stage3: logical / padded stride (52*128)
  const int G2 = 2048, G3 = 2187;       // groups per (b,H)
  const size_t S3e = (size_t)NB * CDIM * Ls3;   // 27,262,976 elements

  // Arena: 3 bf16 slots + P buffer + flags ≈ 183.8 MB.
  char* p = (char*)d_ws;
  auto alloc = [&](size_t bytes) { char* r = p; p += (bytes + 255) & ~(size_t)255; return r; };
  u16* slotA = (u16*)alloc(S3e * 2);   // xT  -> chain-1 buffer
  u16* slotB = (u16*)alloc(S3e * 2);   // qk  -> chain-2 buffer
  u16* slotC = (u16*)alloc(S3e * 2);   // v0 (kept through each stage)
  float* Pbuf = (float*)alloc((size_t)5038848 * 4);  // max(12*32*G2*4, 8*32*G3*9)
  int* flags = (int*)alloc(64 * 4);
  (void)ws_size; (void)n_in; (void)out_size;

  // y2/y3 staging (bf16) lives in the front half of d_out (fp32 buffer,
  // 67 MB; we use the first 33 MB as bf16 scratch until the final GEMM
  // overwrites the whole buffer in fp32).
  u16* ybuf = (u16*)d_out;

  // ---- dtype sniff (writes flags[0..21]; flags[22]=0 = bf16 sentinel) ----
  PtrArgs pa;
  for (int i = 0; i < 22; i++) { pa.p[i] = d_in[i]; pa.n[i] = in_sizes[i]; }
  detect_dtypes<<<23, 256, 0, stream>>>(pa, flags);
  const int BF = 22;  // sentinel flag index (bf16)

  dim3 tb(32, 8);
  const size_t P2lev = (size_t)32 * G2 * 4;
  const size_t P3lev = (size_t)32 * G3 * 9;

  // ================= stage base=2 (n=12, L=4096, no pad) =================
  transpose_pad<<<dim3(Ls2 / 32, CDIM / 32, NB), tb, 0, stream>>>(d_in[0], slotA, W, Ls2, flags, 0);
  gemm_bn<<<dim3(NB * Ls2 / 128, CDIM / 128), 256, 0, stream>>>(
      d_in[1], slotA, slotB, d_in[2], d_in[3], Ls2, flags, 1, 2, 3, 0);
  gemm_bn<<<dim3(NB * Ls2 / 128, CDIM / 128), 256, 0, stream>>>(
      d_in[4], slotA, slotC, d_in[5], d_in[6], Ls2, flags, 4, 5, 6, 0);
  p_compute<2><<<dim3((32 * G2 + 255) / 256, 12), 256, 0, stream>>>(slotB, Pbuf, Ls2, 12, G2);

  {
    const int apply_blocks = (int)(((size_t)4096 * G2) / 256);  // 32768
    for (int idx = 0; idx < 12; idx++) {           // chain v1: i = 11..0 -> slotA
      int i = 11 - idx;
      const u16* src = (idx == 0) ? slotC : slotA;
      apply_level<2><<<apply_blocks, 256, 0, stream>>>(src, slotA, Pbuf + (size_t)i * P2lev,
                                                       ipow(2, 11 - i), G2, Ls2);
    }
    for (int idx = 0; idx < 12; idx++) {           // chain v2: i = 0..11 -> slotB
      int i = idx;
      const u16* src = (idx == 0) ? slotC : slotB;
      apply_level<2><<<apply_blocks, 256, 0, stream>>>(src, slotB, Pbuf + (size_t)i * P2lev,
                                                       ipow(2, 11 - i), G2, Ls2);
    }
  }
  combine_pe<<<(int)(((size_t)NB * CDIM * 4096) / 256), 256, 0, stream>>>(
      d_in[0], slotA, slotB, slotC, d_in[7], d_in[8], d_in[9], ybuf, Ls2, Ls2,
      flags, 0, 7, 8, 9);

  // ================= stage base=3 (n=8, L=6561, stride 6656) =================
  transpose_pad<<<dim3(Ls3 / 32, CDIM / 32, NB), tb, 0, stream>>>(ybuf, slotA, W, Ls3, flags, BF);
  gemm_bn<<<dim3(NB * Ls3 / 128, CDIM / 128), 256, 0, stream>>>(
      d_in[10], slotA, slotB, d_in[11], d_in[12], Ls3, flags, 10, 11, 12, 0);
  gemm_bn<<<dim3(NB * Ls3 / 128, CDIM / 128), 256, 0, stream>>>(
      d_in[13], slotA, slotC, d_in[14], d_in[15], Ls3, flags, 13, 14, 15, 0);
  p_compute<3><<<dim3((32 * G3 + 255) / 256, 8), 256, 0, stream>>>(slotB, Pbuf, Ls3, 8, G3);

  {
    const int apply_blocks = (int)(((size_t)4096 * G3) / 256);  // 34992
    for (int idx = 0; idx < 8; idx++) {            // chain v1: i = 7..0 -> slotA
      int i = 7 - idx;
      const u16* src = (idx == 0) ? slotC : slotA;
      apply_level<3><<<apply_blocks, 256, 0, stream>>>(src, slotA, Pbuf + (size_t)i * P3lev,
                                                       ipow(3, 7 - i), G3, Ls3);
    }
    for (int idx = 0; idx < 8; idx++) {            // chain v2: i = 0..7 -> slotB
      int i = idx;
      const u16* src = (idx == 0) ? slotC : slotB;
      apply_level<3><<<apply_blocks, 256, 0, stream>>>(src, slotB, Pbuf + (size_t)i * P3lev,
                                                       ipow(3, 7 - i), G3, Ls3);
    }
  }
  combine_pe<<<(int)(((size_t)NB * CDIM * 4096) / 256), 256, 0, stream>>>(
      ybuf, slotA, slotB, slotC, d_in[16], d_in[17], d_in[18], ybuf, Ls3, L3,
      flags, BF, 16, 17, 18);

  // ================= final projection (fp32 output!) =================
  transpose_pad<<<dim3(Ls2 / 32, CDIM / 32, NB), tb, 0, stream>>>(ybuf, slotA, W, Ls2, flags, BF);
  gemm_bn<<<dim3(NB * Ls2 / 128, CDIM / 128), 256, 0, stream>>>(
      d_in[19], slotA, d_out, d_in[20], d_in[21], Ls2, flags, 19, 20, 21, 1);
}